// Round 1
// baseline (608.286 us; speedup 1.0000x reference)
//
#include <hip/hip_runtime.h>

#define NROWS 8192
#define DIM   128
#define KSPLIT 8

typedef __attribute__((ext_vector_type(8))) short  short8;
typedef __attribute__((ext_vector_type(4))) float  floatx4;

union frag_u { unsigned u[4]; short8 v; };

// pack two fp32 -> two bf16 (RNE), low word = a
__device__ __forceinline__ unsigned pk_bf16(float a, float b) {
  unsigned ua = __float_as_uint(a);
  ua += 0x7fffu + ((ua >> 16) & 1u);
  unsigned ub = __float_as_uint(b);
  ub += 0x7fffu + ((ub >> 16) & 1u);
  return (ua >> 16) | (ub & 0xffff0000u);
}

// ---------------- kernel 1: row sums of A -> s[i] = 1/(sqrt(d)+1e-8) -------
__global__ __launch_bounds__(256) void k_rowsum(const float* __restrict__ A,
                                                float* __restrict__ s) {
  int row = blockIdx.x;
  const float4* A4 = (const float4*)(A + (size_t)row * NROWS);
  float sum = 0.f;
#pragma unroll
  for (int it = 0; it < NROWS / 4 / 256; ++it) {   // 8 iters
    float4 v = A4[threadIdx.x + it * 256];
    sum += (v.x + v.y) + (v.z + v.w);
  }
#pragma unroll
  for (int off = 32; off > 0; off >>= 1) sum += __shfl_down(sum, off, 64);
  __shared__ float red[4];
  int lane = threadIdx.x & 63, w = threadIdx.x >> 6;
  if (lane == 0) red[w] = sum;
  __syncthreads();
  if (threadIdx.x == 0) {
    float d = (red[0] + red[1]) + (red[2] + red[3]);
    s[row] = 1.0f / (sqrtf(d) + 1e-8f);
  }
}

// ------------- kernel 2: gT[k][j] = bf16( s_j * (V@W + b)[j][k] ) ----------
__global__ __launch_bounds__(256) void k_fc(const float* __restrict__ V,
                                            const float* __restrict__ W,
                                            const float* __restrict__ b,
                                            const float* __restrict__ s,
                                            unsigned short* __restrict__ gT) {
  __shared__ float Wl[DIM * DIM];          // 64 KB
  __shared__ float Vl[32 * DIM];           // 16 KB
  __shared__ unsigned short Fl[32 * DIM];  // 8 KB (bf16 block, row-major)
  int r0 = blockIdx.x * 32;
  {
    const float4* Wg = (const float4*)W;
    float4* Wd = (float4*)Wl;
#pragma unroll
    for (int i = 0; i < DIM * DIM / 4 / 256; ++i)  // 16
      Wd[threadIdx.x + i * 256] = Wg[threadIdx.x + i * 256];
    const float4* Vg = (const float4*)(V + (size_t)r0 * DIM);
    float4* Vd = (float4*)Vl;
#pragma unroll
    for (int i = 0; i < 32 * DIM / 4 / 256; ++i)   // 4
      Vd[threadIdx.x + i * 256] = Vg[threadIdx.x + i * 256];
  }
  __syncthreads();

  int cg = threadIdx.x & 31;   // 32 col groups of 4
  int rg = threadIdx.x >> 5;   // 8 row groups of 4
  float acc[4][4] = {};
  for (int d = 0; d < DIM; ++d) {
    float4 w = *(const float4*)&Wl[d * DIM + cg * 4];
#pragma unroll
    for (int rr = 0; rr < 4; ++rr) {
      float v = Vl[(rg * 4 + rr) * DIM + d];
      acc[rr][0] += v * w.x; acc[rr][1] += v * w.y;
      acc[rr][2] += v * w.z; acc[rr][3] += v * w.w;
    }
  }
  float bb[4], sv[4];
#pragma unroll
  for (int cc = 0; cc < 4; ++cc) bb[cc] = b[cg * 4 + cc];
#pragma unroll
  for (int rr = 0; rr < 4; ++rr) sv[rr] = s[r0 + rg * 4 + rr];
#pragma unroll
  for (int rr = 0; rr < 4; ++rr)
#pragma unroll
    for (int cc = 0; cc < 4; cc += 2) {
      unsigned p = pk_bf16((acc[rr][cc]     + bb[cc])     * sv[rr],
                           (acc[rr][cc + 1] + bb[cc + 1]) * sv[rr]);
      *(unsigned*)&Fl[(rg * 4 + rr) * DIM + cg * 4 + cc] = p;
    }
  __syncthreads();

  // transposed write: gT row k gets 16 consecutive j values (32 B)
  int k = threadIdx.x & 127, h = threadIdx.x >> 7;
  unsigned wb[8];
#pragma unroll
  for (int rr = 0; rr < 8; ++rr) {
    unsigned lo = Fl[(h * 16 + 2 * rr) * DIM + k];
    unsigned hi = Fl[(h * 16 + 2 * rr + 1) * DIM + k];
    wb[rr] = lo | (hi << 16);
  }
  uint4* dst = (uint4*)(gT + (size_t)k * NROWS + r0 + h * 16);
  dst[0] = make_uint4(wb[0], wb[1], wb[2], wb[3]);
  dst[1] = make_uint4(wb[4], wb[5], wb[6], wb[7]);
}

// ------------- kernel 3: out[i][k] += s_i * sum_j A[i][j] * gT[k][j] -------
// outT = gT (A-operand, [m=kout][k=j]) x adjacency (B-operand, row-major = B^T form)
// wave tile: 128 kout x 32 i, K-split 8 (j-extent 1024). 2048 waves total.
__global__ __launch_bounds__(256, 2) void k_spmm(const float* __restrict__ A,
                                                 const unsigned short* __restrict__ gT,
                                                 const float* __restrict__ s,
                                                 float* __restrict__ out) {
  int tid  = threadIdx.x;
  int widx = tid >> 6, lane = tid & 63;
  int gid  = blockIdx.x * 4 + widx;
  int iblk = gid >> 3;                 // 0..255
  int ks   = gid & 7;                  // 0..7
  int i0   = iblk * 32;
  int j0   = ks * (NROWS / KSPLIT);    // 1024-wide j slice
  int l15 = lane & 15, quad = lane >> 4;

  floatx4 acc[8][2];
#pragma unroll
  for (int mt = 0; mt < 8; ++mt)
#pragma unroll
    for (int nt = 0; nt < 2; ++nt)
      acc[mt][nt] = (floatx4){0.f, 0.f, 0.f, 0.f};

  const unsigned short* gp  = gT + (size_t)l15 * NROWS + j0 + quad * 8;
  const float*          ap0 = A + (size_t)(i0 + l15) * NROWS + j0 + quad * 8;
  const float*          ap1 = ap0 + (size_t)16 * NROWS;

#pragma unroll 2
  for (int jj = 0; jj < NROWS / KSPLIT; jj += 32) {
    short8 bfrag[2];
    {
      float4 lo = *(const float4*)(ap0);
      float4 hi = *(const float4*)(ap0 + 4);
      frag_u f;
      f.u[0] = pk_bf16(lo.x, lo.y); f.u[1] = pk_bf16(lo.z, lo.w);
      f.u[2] = pk_bf16(hi.x, hi.y); f.u[3] = pk_bf16(hi.z, hi.w);
      bfrag[0] = f.v;
    }
    {
      float4 lo = *(const float4*)(ap1);
      float4 hi = *(const float4*)(ap1 + 4);
      frag_u f;
      f.u[0] = pk_bf16(lo.x, lo.y); f.u[1] = pk_bf16(lo.z, lo.w);
      f.u[2] = pk_bf16(hi.x, hi.y); f.u[3] = pk_bf16(hi.z, hi.w);
      bfrag[1] = f.v;
    }
    short8 afrag[8];
#pragma unroll
    for (int mt = 0; mt < 8; ++mt)
      afrag[mt] = *(const short8*)(gp + mt * 16 * NROWS);
#pragma unroll
    for (int mt = 0; mt < 8; ++mt) {
      acc[mt][0] = __builtin_amdgcn_mfma_f32_16x16x32_bf16(afrag[mt], bfrag[0], acc[mt][0], 0, 0, 0);
      acc[mt][1] = __builtin_amdgcn_mfma_f32_16x16x32_bf16(afrag[mt], bfrag[1], acc[mt][1], 0, 0, 0);
    }
    gp += 32; ap0 += 32; ap1 += 32;
  }

  // epilogue: D[row=kout-part][col=i-part]; lane holds 4 consecutive kout at fixed i
#pragma unroll
  for (int nt = 0; nt < 2; ++nt) {
    int i = i0 + nt * 16 + l15;
    float si = s[i];
    float* orow = out + (size_t)i * DIM;
#pragma unroll
    for (int mt = 0; mt < 8; ++mt)
#pragma unroll
      for (int r = 0; r < 4; ++r) {
        int kout = mt * 16 + quad * 4 + r;
        __hip_atomic_fetch_add(&orow[kout], si * acc[mt][nt][r],
                               __ATOMIC_RELAXED, __HIP_MEMORY_SCOPE_AGENT);
      }
  }
}

extern "C" void kernel_launch(void* const* d_in, const int* in_sizes, int n_in,
                              void* d_out, int out_size, void* d_ws, size_t ws_size,
                              hipStream_t stream) {
  const float* values    = (const float*)d_in[0];
  const float* adjacency = (const float*)d_in[1];
  const float* W         = (const float*)d_in[2];
  const float* b         = (const float*)d_in[3];
  float* out = (float*)d_out;

  float* s = (float*)d_ws;                                        // 32 KB
  unsigned short* gT = (unsigned short*)((char*)d_ws + 32768);    // 2 MB bf16 [128][8192]

  hipMemsetAsync(out, 0, (size_t)NROWS * DIM * sizeof(float), stream);
  k_rowsum<<<NROWS, 256, 0, stream>>>(adjacency, s);
  k_fc<<<NROWS / 32, 256, 0, stream>>>(values, W, b, s, gT);
  k_spmm<<<512, 256, 0, stream>>>(adjacency, gT, s, out);
}

// Round 2
// 523.587 us; speedup vs baseline: 1.1618x; 1.1618x over previous
//
#include <hip/hip_runtime.h>

#define NROWS 8192
#define DIM   128
#define RSTRIDE 136   // padded dwords per LDS tile row (16B-aligned, conflict-light)

typedef __attribute__((ext_vector_type(8))) short  short8;
typedef __attribute__((ext_vector_type(4))) float  floatx4;

union frag_u { unsigned u[4]; short8 v; };

// pack two fp32 -> two bf16 (RNE), low word = a
__device__ __forceinline__ unsigned pk_bf16(float a, float b) {
  unsigned ua = __float_as_uint(a);
  ua += 0x7fffu + ((ua >> 16) & 1u);
  unsigned ub = __float_as_uint(b);
  ub += 0x7fffu + ((ub >> 16) & 1u);
  return (ua >> 16) | (ub & 0xffff0000u);
}

// ---------------- kernel 1: row sums of A -> s[i] = 1/(sqrt(d)+1e-8) -------
__global__ __launch_bounds__(256) void k_rowsum(const float* __restrict__ A,
                                                float* __restrict__ s) {
  int row = blockIdx.x;
  const float4* A4 = (const float4*)(A + (size_t)row * NROWS);
  float sum = 0.f;
#pragma unroll
  for (int it = 0; it < NROWS / 4 / 256; ++it) {   // 8 iters
    float4 v = A4[threadIdx.x + it * 256];
    sum += (v.x + v.y) + (v.z + v.w);
  }
#pragma unroll
  for (int off = 32; off > 0; off >>= 1) sum += __shfl_down(sum, off, 64);
  __shared__ float red[4];
  int lane = threadIdx.x & 63, w = threadIdx.x >> 6;
  if (lane == 0) red[w] = sum;
  __syncthreads();
  if (threadIdx.x == 0) {
    float d = (red[0] + red[1]) + (red[2] + red[3]);
    s[row] = 1.0f / (sqrtf(d) + 1e-8f);
  }
}

// ------------- kernel 2: gT[k][j] = bf16( s_j * (V@W + b)[j][k] ) ----------
__global__ __launch_bounds__(256) void k_fc(const float* __restrict__ V,
                                            const float* __restrict__ W,
                                            const float* __restrict__ b,
                                            const float* __restrict__ s,
                                            unsigned short* __restrict__ gT) {
  __shared__ float Wl[DIM * DIM];          // 64 KB
  __shared__ float Vl[32 * DIM];           // 16 KB
  __shared__ unsigned short Fl[32 * DIM];  // 8 KB (bf16 block, row-major)
  int r0 = blockIdx.x * 32;
  {
    const float4* Wg = (const float4*)W;
    float4* Wd = (float4*)Wl;
#pragma unroll
    for (int i = 0; i < DIM * DIM / 4 / 256; ++i)  // 16
      Wd[threadIdx.x + i * 256] = Wg[threadIdx.x + i * 256];
    const float4* Vg = (const float4*)(V + (size_t)r0 * DIM);
    float4* Vd = (float4*)Vl;
#pragma unroll
    for (int i = 0; i < 32 * DIM / 4 / 256; ++i)   // 4
      Vd[threadIdx.x + i * 256] = Vg[threadIdx.x + i * 256];
  }
  __syncthreads();

  int cg = threadIdx.x & 31;   // 32 col groups of 4
  int rg = threadIdx.x >> 5;   // 8 row groups of 4
  float acc[4][4] = {};
  for (int d = 0; d < DIM; ++d) {
    float4 w = *(const float4*)&Wl[d * DIM + cg * 4];
#pragma unroll
    for (int rr = 0; rr < 4; ++rr) {
      float v = Vl[(rg * 4 + rr) * DIM + d];
      acc[rr][0] += v * w.x; acc[rr][1] += v * w.y;
      acc[rr][2] += v * w.z; acc[rr][3] += v * w.w;
    }
  }
  float bb[4], sv[4];
#pragma unroll
  for (int cc = 0; cc < 4; ++cc) bb[cc] = b[cg * 4 + cc];
#pragma unroll
  for (int rr = 0; rr < 4; ++rr) sv[rr] = s[r0 + rg * 4 + rr];
#pragma unroll
  for (int rr = 0; rr < 4; ++rr)
#pragma unroll
    for (int cc = 0; cc < 4; cc += 2) {
      unsigned p = pk_bf16((acc[rr][cc]     + bb[cc])     * sv[rr],
                           (acc[rr][cc + 1] + bb[cc + 1]) * sv[rr]);
      *(unsigned*)&Fl[(rg * 4 + rr) * DIM + cg * 4 + cc] = p;
    }
  __syncthreads();

  // transposed write: gT row k gets 16 consecutive j values (32 B)
  int k = threadIdx.x & 127, h = threadIdx.x >> 7;
  unsigned wb[8];
#pragma unroll
  for (int rr = 0; rr < 8; ++rr) {
    unsigned lo = Fl[(h * 16 + 2 * rr) * DIM + k];
    unsigned hi = Fl[(h * 16 + 2 * rr + 1) * DIM + k];
    wb[rr] = lo | (hi << 16);
  }
  uint4* dst = (uint4*)(gT + (size_t)k * NROWS + r0 + h * 16);
  dst[0] = make_uint4(wb[0], wb[1], wb[2], wb[3]);
  dst[1] = make_uint4(wb[4], wb[5], wb[6], wb[7]);
}

// ------------- kernel 3: out[i][k] = s_i * sum_j A[i][j] * gT[k][j] --------
// Block = 512 threads = 8 waves. Block owns a 16-row i-tile, full kout=128.
// Wave w handles j-slice [w*1024, (w+1)*1024). Split-K reduced in LDS, then
// one coalesced scaled store. No atomics, no out memset.
__global__ __launch_bounds__(512, 4) void k_spmm(const float* __restrict__ A,
                                                 const unsigned short* __restrict__ gT,
                                                 const float* __restrict__ s,
                                                 float* __restrict__ out) {
  __shared__ float red[8 * 16 * RSTRIDE];   // 69.6 KB
  int tid  = threadIdx.x;
  int w    = tid >> 6, lane = tid & 63;
  int l15  = lane & 15, quad = lane >> 4;
  int i0   = blockIdx.x * 16;
  int j0   = w * (NROWS / 8);               // 1024-wide j slice

  floatx4 acc[8];
#pragma unroll
  for (int mt = 0; mt < 8; ++mt) acc[mt] = (floatx4){0.f, 0.f, 0.f, 0.f};

  const unsigned short* gp = gT + (size_t)l15 * NROWS + j0 + quad * 8;
  const float*          ap = A + (size_t)(i0 + l15) * NROWS + j0 + quad * 8;

#pragma unroll 2
  for (int jj = 0; jj < NROWS / 8; jj += 32) {
    short8 bfrag;
    {
      float4 lo = *(const float4*)(ap);
      float4 hi = *(const float4*)(ap + 4);
      frag_u f;
      f.u[0] = pk_bf16(lo.x, lo.y); f.u[1] = pk_bf16(lo.z, lo.w);
      f.u[2] = pk_bf16(hi.x, hi.y); f.u[3] = pk_bf16(hi.z, hi.w);
      bfrag = f.v;
    }
    short8 afrag[8];
#pragma unroll
    for (int mt = 0; mt < 8; ++mt)
      afrag[mt] = *(const short8*)(gp + mt * 16 * NROWS);
#pragma unroll
    for (int mt = 0; mt < 8; ++mt)
      acc[mt] = __builtin_amdgcn_mfma_f32_16x16x32_bf16(afrag[mt], bfrag, acc[mt], 0, 0, 0);
    gp += 32; ap += 32;
  }

  // stash wave tile: red[w][l15][kout], kout = mt*16 + quad*4 + r
  float* myred = red + w * 16 * RSTRIDE + l15 * RSTRIDE + quad * 4;
#pragma unroll
  for (int mt = 0; mt < 8; ++mt) {
    float4 v = make_float4(acc[mt][0], acc[mt][1], acc[mt][2], acc[mt][3]);
    *(float4*)(myred + mt * 16) = v;
  }
  __syncthreads();

  // reduce 8 wave tiles, scale by s_i, store coalesced
  int row = tid >> 5;             // 0..15
  int c4  = (tid & 31) * 4;       // 0..124
  float4 sum = make_float4(0.f, 0.f, 0.f, 0.f);
#pragma unroll
  for (int ww = 0; ww < 8; ++ww) {
    float4 v = *(const float4*)(red + ww * 16 * RSTRIDE + row * RSTRIDE + c4);
    sum.x += v.x; sum.y += v.y; sum.z += v.z; sum.w += v.w;
  }
  float si = s[i0 + row];
  sum.x *= si; sum.y *= si; sum.z *= si; sum.w *= si;
  *(float4*)(out + (size_t)(i0 + row) * DIM + c4) = sum;
}

extern "C" void kernel_launch(void* const* d_in, const int* in_sizes, int n_in,
                              void* d_out, int out_size, void* d_ws, size_t ws_size,
                              hipStream_t stream) {
  const float* values    = (const float*)d_in[0];
  const float* adjacency = (const float*)d_in[1];
  const float* W         = (const float*)d_in[2];
  const float* b         = (const float*)d_in[3];
  float* out = (float*)d_out;

  float* s = (float*)d_ws;                                        // 32 KB
  unsigned short* gT = (unsigned short*)((char*)d_ws + 32768);    // 2 MB bf16 [128][8192]

  k_rowsum<<<NROWS, 256, 0, stream>>>(adjacency, s);
  k_fc<<<NROWS / 32, 256, 0, stream>>>(values, W, b, s, gT);
  k_spmm<<<NROWS / 16, 512, 0, stream>>>(adjacency, gT, s, out);
}

// Round 3
// 449.672 us; speedup vs baseline: 1.3527x; 1.1644x over previous
//
#include <hip/hip_runtime.h>

#define NROWS 8192
#define DIM   128
#define RS    132    // spmm LDS reduce row stride (dwords)
#define PSTR  520    // k_prep LDS row stride (shorts) = 260 dwords -> 2-way banks

typedef __attribute__((ext_vector_type(8))) short  short8;
typedef __attribute__((ext_vector_type(4))) float  floatx4;

// pack two fp32 -> two bf16 (RNE), low word = a
__device__ __forceinline__ unsigned pk_bf16(float a, float b) {
  unsigned ua = __float_as_uint(a);
  ua += 0x7fffu + ((ua >> 16) & 1u);
  unsigned ub = __float_as_uint(b);
  ub += 0x7fffu + ((ub >> 16) & 1u);
  return (ua >> 16) | (ub & 0xffff0000u);
}

// ---- kernel 1: fused rowsum + bf16-tile conversion of A --------------------
// Tile layout: Abf[((iblk*256 + jblk)*64 + L)*8 + e], L = quad*16 + l15:
//   row i = iblk*16 + l15, col j = jblk*32 + quad*8 + e  (MFMA B-operand frag)
__global__ __launch_bounds__(256) void k_prep(const float* __restrict__ A,
                                              float* __restrict__ d,
                                              unsigned short* __restrict__ Abf) {
  __shared__ unsigned short B[16 * PSTR];   // 16.6 KB
  __shared__ float rsum[16 * 17];
  int iblk = blockIdx.x;            // 0..511
  int wb   = blockIdx.y;            // 0..15
  int i0   = iblk * 16;
  int jwin = wb * 512;
  int t = threadIdx.x;
  int r = t >> 4, l16 = t & 15;

  const float* ap = A + (size_t)(i0 + r) * NROWS + jwin + l16 * 8;
  float sum = 0.f;
#pragma unroll
  for (int it = 0; it < 4; ++it) {
    float4 lo = *(const float4*)(ap + it * 128);
    float4 hi = *(const float4*)(ap + it * 128 + 4);
    sum += (lo.x + lo.y) + (lo.z + lo.w) + (hi.x + hi.y) + (hi.z + hi.w);
    uint4 p = make_uint4(pk_bf16(lo.x, lo.y), pk_bf16(lo.z, lo.w),
                         pk_bf16(hi.x, hi.y), pk_bf16(hi.z, hi.w));
    *(uint4*)&B[r * PSTR + l16 * 8 + it * 128] = p;
  }
  rsum[r * 17 + l16] = sum;
  __syncthreads();
  if (t < 16) {
    float s2 = 0.f;
#pragma unroll
    for (int c = 0; c < 16; ++c) s2 += rsum[t * 17 + c];
    atomicAdd(&d[i0 + t], s2);
  }
  // tiled write: 16 tiles (jb), 16 threads each, 4 lane-slots per thread
  int jb = t >> 4, p = t & 15;
  unsigned short* tbase = Abf + ((size_t)iblk * 256 + wb * 16 + jb) * 512;
#pragma unroll
  for (int q = 0; q < 4; ++q) {
    uint4 v = *(const uint4*)&B[p * PSTR + jb * 32 + q * 8];
    *(uint4*)(tbase + (size_t)(q * 16 + p) * 8) = v;
  }
}

__global__ __launch_bounds__(256) void k_sconv(const float* __restrict__ d,
                                               float* __restrict__ s) {
  int i = blockIdx.x * 256 + threadIdx.x;
  s[i] = 1.0f / (sqrtf(d[i]) + 1e-8f);
}

// ---- kernel 2: gT tiles: gTt tile[kblk][jblk], lane L: kout=kblk*16+(L&15),
//      j = jblk*32 + (L>>4)*8 + e   (MFMA A-operand frag), value s_j*fc[j][k]
__global__ __launch_bounds__(256) void k_fc(const float* __restrict__ V,
                                            const float* __restrict__ W,
                                            const float* __restrict__ b,
                                            const float* __restrict__ s,
                                            unsigned short* __restrict__ gTt) {
  __shared__ float Wl[DIM * DIM];          // 64 KB
  __shared__ float Vl[32 * DIM];           // 16 KB
  __shared__ unsigned short Fl[32 * DIM];  // 8 KB  [j_local][k]
  int r0 = blockIdx.x * 32;
  {
    const float4* Wg = (const float4*)W;
    float4* Wd = (float4*)Wl;
#pragma unroll
    for (int i = 0; i < DIM * DIM / 4 / 256; ++i)
      Wd[threadIdx.x + i * 256] = Wg[threadIdx.x + i * 256];
    const float4* Vg = (const float4*)(V + (size_t)r0 * DIM);
    float4* Vd = (float4*)Vl;
#pragma unroll
    for (int i = 0; i < 32 * DIM / 4 / 256; ++i)
      Vd[threadIdx.x + i * 256] = Vg[threadIdx.x + i * 256];
  }
  __syncthreads();

  int cg = threadIdx.x & 31;
  int rg = threadIdx.x >> 5;
  float acc[4][4] = {};
  for (int dd = 0; dd < DIM; ++dd) {
    float4 w = *(const float4*)&Wl[dd * DIM + cg * 4];
#pragma unroll
    for (int rr = 0; rr < 4; ++rr) {
      float v = Vl[(rg * 4 + rr) * DIM + dd];
      acc[rr][0] += v * w.x; acc[rr][1] += v * w.y;
      acc[rr][2] += v * w.z; acc[rr][3] += v * w.w;
    }
  }
  float bb[4], sv[4];
#pragma unroll
  for (int cc = 0; cc < 4; ++cc) bb[cc] = b[cg * 4 + cc];
#pragma unroll
  for (int rr = 0; rr < 4; ++rr) sv[rr] = s[r0 + rg * 4 + rr];
#pragma unroll
  for (int rr = 0; rr < 4; ++rr)
#pragma unroll
    for (int cc = 0; cc < 4; cc += 2) {
      unsigned p = pk_bf16((acc[rr][cc]     + bb[cc])     * sv[rr],
                           (acc[rr][cc + 1] + bb[cc + 1]) * sv[rr]);
      *(unsigned*)&Fl[(rg * 4 + rr) * DIM + cg * 4 + cc] = p;
    }
  __syncthreads();

  int kblk = threadIdx.x >> 5, s5 = threadIdx.x & 31;
  int jblk = r0 >> 5;
#pragma unroll
  for (int h = 0; h < 2; ++h) {
    int L = s5 + h * 32;
    int l15 = L & 15, quad = L >> 4;
    int k = kblk * 16 + l15;
    unsigned w0 = (unsigned)Fl[(quad * 8 + 0) * DIM + k] | ((unsigned)Fl[(quad * 8 + 1) * DIM + k] << 16);
    unsigned w1 = (unsigned)Fl[(quad * 8 + 2) * DIM + k] | ((unsigned)Fl[(quad * 8 + 3) * DIM + k] << 16);
    unsigned w2 = (unsigned)Fl[(quad * 8 + 4) * DIM + k] | ((unsigned)Fl[(quad * 8 + 5) * DIM + k] << 16);
    unsigned w3 = (unsigned)Fl[(quad * 8 + 6) * DIM + k] | ((unsigned)Fl[(quad * 8 + 7) * DIM + k] << 16);
    *(uint4*)(gTt + ((size_t)(kblk * 256 + jblk) * 64 + L) * 8) = make_uint4(w0, w1, w2, w3);
  }
}

// ---- kernel 3: partial[ks][bi] = gTt x Abf over j-slice (all loads 1KB/wave)
// block: 4 waves, tile 32 i x 128 kout, wave w covers j in [ks*2048+w*512, +512)
__global__ __launch_bounds__(256, 4) void k_spmm(const unsigned short* __restrict__ Abf,
                                                 const unsigned short* __restrict__ gTt,
                                                 float* __restrict__ partial) {
  __shared__ float red[4 * 32 * RS];   // 67.6 KB
  int t = threadIdx.x, w = t >> 6, lane = t & 63;
  int bi = blockIdx.x >> 2, ks = blockIdx.x & 3;
  int jblk0 = ks * 64 + w * 16;        // (ks*2048 + w*512)/32

  const unsigned short* ab = Abf + ((size_t)bi * 2 * 256 + jblk0) * 512 + lane * 8;
  const unsigned short* gb = gTt + (size_t)jblk0 * 512 + lane * 8;

  floatx4 acc[8][2];
#pragma unroll
  for (int kb = 0; kb < 8; ++kb)
#pragma unroll
    for (int ib = 0; ib < 2; ++ib)
      acc[kb][ib] = (floatx4){0.f, 0.f, 0.f, 0.f};

#pragma unroll 2
  for (int it = 0; it < 16; ++it) {
    short8 af0 = *(const short8*)(ab);
    short8 af1 = *(const short8*)(ab + (size_t)256 * 512);
    short8 gf[8];
#pragma unroll
    for (int kb = 0; kb < 8; ++kb)
      gf[kb] = *(const short8*)(gb + (size_t)kb * 256 * 512);
#pragma unroll
    for (int kb = 0; kb < 8; ++kb) {
      acc[kb][0] = __builtin_amdgcn_mfma_f32_16x16x32_bf16(gf[kb], af0, acc[kb][0], 0, 0, 0);
      acc[kb][1] = __builtin_amdgcn_mfma_f32_16x16x32_bf16(gf[kb], af1, acc[kb][1], 0, 0, 0);
    }
    ab += 512; gb += 512;
  }

  int l15 = lane & 15, quad = lane >> 4;
  float* myred = red + w * 32 * RS;
#pragma unroll
  for (int ib = 0; ib < 2; ++ib)
#pragma unroll
    for (int kb = 0; kb < 8; ++kb) {
      float4 v = make_float4(acc[kb][ib][0], acc[kb][ib][1], acc[kb][ib][2], acc[kb][ib][3]);
      *(float4*)(myred + (ib * 16 + l15) * RS + kb * 16 + quad * 4) = v;
    }
  __syncthreads();

  int ii = t >> 3, kg = (t & 7) * 16;
  float4 sum[4];
#pragma unroll
  for (int c = 0; c < 4; ++c) sum[c] = make_float4(0.f, 0.f, 0.f, 0.f);
#pragma unroll
  for (int ww = 0; ww < 4; ++ww)
#pragma unroll
    for (int c = 0; c < 4; ++c) {
      float4 v = *(const float4*)(red + ww * 32 * RS + ii * RS + kg + c * 4);
      sum[c].x += v.x; sum[c].y += v.y; sum[c].z += v.z; sum[c].w += v.w;
    }
  float* pout = partial + ((size_t)(ks * 256 + bi) * 32 + ii) * 128 + kg;
#pragma unroll
  for (int c = 0; c < 4; ++c) *(float4*)(pout + c * 4) = sum[c];
}

// ---- kernel 4: out[i][k] = s_i * sum_ks partial[ks][i][k] ------------------
__global__ __launch_bounds__(256) void k_reduce(const float* __restrict__ partial,
                                                const float* __restrict__ s,
                                                float* __restrict__ out) {
  int g = blockIdx.x * 256 + threadIdx.x;    // 0..262143
  int i = g >> 5, c4 = (g & 31) * 4;
  size_t base = (size_t)i * 128 + c4;
  const size_t kstr = (size_t)256 * 32 * 128;
  float4 a = *(const float4*)(partial + base);
  float4 bq = *(const float4*)(partial + base + kstr);
  float4 c = *(const float4*)(partial + base + 2 * kstr);
  float4 dq = *(const float4*)(partial + base + 3 * kstr);
  float si = s[i];
  float4 r;
  r.x = si * (a.x + bq.x + c.x + dq.x);
  r.y = si * (a.y + bq.y + c.y + dq.y);
  r.z = si * (a.z + bq.z + c.z + dq.z);
  r.w = si * (a.w + bq.w + c.w + dq.w);
  *(float4*)(out + base) = r;
}

extern "C" void kernel_launch(void* const* d_in, const int* in_sizes, int n_in,
                              void* d_out, int out_size, void* d_ws, size_t ws_size,
                              hipStream_t stream) {
  const float* values    = (const float*)d_in[0];
  const float* adjacency = (const float*)d_in[1];
  const float* W         = (const float*)d_in[2];
  const float* b         = (const float*)d_in[3];
  float* out = (float*)d_out;

  char* ws = (char*)d_ws;
  float* d            = (float*)ws;                         // 32 KB
  float* s            = (float*)(ws + 32768);               // 32 KB
  unsigned short* gTt = (unsigned short*)(ws + 65536);      // 2 MB
  float* partial      = (float*)(ws + 65536 + 2097152);     // 16 MB
  unsigned short* Abf = (unsigned short*)(ws + 33554432);   // 128 MB

  hipMemsetAsync(d, 0, NROWS * sizeof(float), stream);
  k_prep<<<dim3(512, 16), 256, 0, stream>>>(adjacency, d, Abf);
  k_sconv<<<NROWS / 256, 256, 0, stream>>>(d, s);
  k_fc<<<NROWS / 32, 256, 0, stream>>>(values, W, b, s, gTt);
  k_spmm<<<1024, 256, 0, stream>>>(Abf, gTt, partial);
  k_reduce<<<NROWS * 32 / 256, 256, 0, stream>>>(partial, s, out);
}